// Round 1
// 552.263 us; speedup vs baseline: 1.0679x; 1.0679x over previous
//
#include <hip/hip_runtime.h>

typedef unsigned short u16;
typedef unsigned int u32;

typedef __attribute__((ext_vector_type(8))) short short8;
typedef __attribute__((ext_vector_type(4))) float floatx4;
typedef __attribute__((ext_vector_type(16))) float floatx16;
typedef __attribute__((ext_vector_type(2))) unsigned int uint2v;
typedef __attribute__((ext_vector_type(4))) unsigned int uint4v;

// ---------- bf16 helpers ----------
static __device__ __forceinline__ u16 f2b(float f) {
    union { float f; u32 i; } v; v.f = f;
    u32 r = v.i + 0x7fffu + ((v.i >> 16) & 1u);
    return (u16)(r >> 16);
}
// 2^x via v_exp_f32
static __device__ __forceinline__ float exp2f_hw(float x) {
    return __builtin_amdgcn_exp2f(x);
}
// pack two f32 -> bf16x2 dword (RNE) in one instruction
static __device__ __forceinline__ u32 cvtpk(float lo, float hi) {
    u32 r;
    asm("v_cvt_pk_bf16_f32 %0, %1, %2" : "=v"(r) : "v"(lo), "v"(hi));
    return r;
}

static __device__ __forceinline__ floatx4 mfma16(short8 a, short8 b, floatx4 c) {
    return __builtin_amdgcn_mfma_f32_16x16x32_bf16(a, b, c, 0, 0, 0);
}
static __device__ __forceinline__ floatx16 mfma32(short8 a, short8 b, floatx16 c) {
    return __builtin_amdgcn_mfma_f32_32x32x16_bf16(a, b, c, 0, 0, 0);
}

// async global->LDS, 16B per lane; LDS dest must be wave-uniform base (HW adds lane*16)
typedef __attribute__((address_space(1))) const void gas_void;
typedef __attribute__((address_space(3))) void las_void;
static __device__ __forceinline__ void gl_lds16(const void* g, void* l) {
    __builtin_amdgcn_global_load_lds((gas_void*)g, (las_void*)l, 16, 0, 0);
}

#define B_ 4
#define S_ 2048
#define D_ 1024
#define H_ 16
#define DH_ 64
#define F_ 4096
#define QKVS 3072   // row stride of fused qkv output

// (1/8) * log2(e), folded into wq/bq so logits come out in exp2 domain
#define QSCALE 0.18033688011112042f

// ---------- cast fp32 -> bf16, 4 elems/thread ----------
__global__ __launch_bounds__(256) void cast_b(const float* __restrict__ in,
                                              u16* __restrict__ out, int n4) {
    int id = blockIdx.x * 256 + threadIdx.x;
    if (id < n4) {
        float4 v = ((const float4*)in)[id];
        ushort4 u;
        u.x = f2b(v.x); u.y = f2b(v.y); u.z = f2b(v.z); u.w = f2b(v.w);
        ((ushort4*)out)[id] = u;
    }
}

// ---------- concat + scale bias: [bq*QSCALE | bk | bv] -> 3072 floats ----------
__global__ __launch_bounds__(256) void concat_bias(const float* __restrict__ bq,
                                                   const float* __restrict__ bk,
                                                   const float* __restrict__ bv,
                                                   float* __restrict__ o) {
    int i = blockIdx.x * 256 + threadIdx.x;
    float v;
    if (i < 1024) v = bq[i] * QSCALE;
    else if (i < 2048) v = bk[i - 1024];
    else v = bv[i - 2048];
    o[i] = v;
}

// ---------- transpose + cast + scale: in [R x C] fp32 -> out [C x R] bf16 ----------
__global__ void transpose_cast(const float* __restrict__ in, u16* __restrict__ out,
                               int R, int C, float scale) {
    __shared__ float t[32][33];
    int bx = blockIdx.x;  // over C
    int by = blockIdx.y;  // over R
    int x = threadIdx.x, y = threadIdx.y;  // 32x8
#pragma unroll
    for (int i = 0; i < 4; ++i) {
        int r = by * 32 + y + i * 8;
        t[y + i * 8][x] = in[(size_t)r * C + bx * 32 + x];
    }
    __syncthreads();
#pragma unroll
    for (int i = 0; i < 4; ++i) {
        int c = bx * 32 + y + i * 8;
        out[(size_t)c * R + by * 32 + x] = f2b(t[x][y + i * 8] * scale);
    }
}

// ---------- transpose V: qkv[B*S, 3072] cols 2048.. -> vt [B,H,DH,S] bf16 ----------
__global__ void transpose_v(const u16* __restrict__ qkv, u16* __restrict__ vt) {
    __shared__ u16 t[32][33];
    int bh = blockIdx.z; int b = bh >> 4, h = bh & 15;
    int s0 = blockIdx.x * 32, d0 = blockIdx.y * 32;
    int x = threadIdx.x, y = threadIdx.y;  // 32x8
#pragma unroll
    for (int i = 0; i < 4; ++i)
        t[y + i * 8][x] =
            qkv[(size_t)(b * S_ + s0 + y + i * 8) * QKVS + 2048 + h * DH_ + d0 + x];
    __syncthreads();
#pragma unroll
    for (int i = 0; i < 4; ++i)
        vt[((size_t)bh * DH_ + d0 + y + i * 8) * S_ + s0 + x] = t[x][y + i * 8];
}

// ---------- generic bf16 GEMM v2: C[M,N] = A[M,K] @ Bt[N,K]^T (+bias)(+relu) ----------
// 128x128 tile, 256 threads (4 waves in 2x2 of 64x64), BK=64 (32 MFMA/barrier),
// global_load_lds width=16 staging with 8-chunk XOR swizzle:
// LDS chunk c of row r holds global chunk c^(r&7) -> ds_read_b128 frags conflict-free.
__global__ __launch_bounds__(256) void gemm_bt(const u16* __restrict__ A,
                                               const u16* __restrict__ Bt,
                                               const float* __restrict__ bias,
                                               float* __restrict__ outF,
                                               u16* __restrict__ outB,
                                               int M, int N, int K, int relu) {
    __shared__ __align__(16) u16 sA[128 * 64];   // 16 KB
    __shared__ __align__(16) u16 sB[128 * 64];   // 16 KB

    int tid = threadIdx.x;
    int w = tid >> 6, lane = tid & 63, quad = lane >> 4, l = lane & 15;
    int wr = w >> 1, wc = w & 1;
    int bM = blockIdx.y, bN = blockIdx.x;

    floatx4 acc[4][4];
#pragma unroll
    for (int i = 0; i < 4; ++i)
#pragma unroll
        for (int j = 0; j < 4; ++j) acc[i][j] = (floatx4){0.f, 0.f, 0.f, 0.f};

    // staging coords: r = row within 8-row slab, c = LDS chunk; fetch global chunk c^r
    int r = lane >> 3;            // 0..7
    int c = lane & 7;             // 0..7
    int cg = ((c ^ r) << 3);      // global chunk offset in elems
    const u16* gA = &A[(size_t)(bM * 128 + r) * K + cg];
    const u16* gB = &Bt[(size_t)(bN * 128 + r) * K + cg];

    int l7 = l & 7;

    for (int kk = 0; kk < K; kk += 64) {
#pragma unroll
        for (int hh = 0; hh < 4; ++hh) {
            int rowbase = hh * 32 + w * 8;            // multiple of 8
            gl_lds16(gA + (size_t)rowbase * K + kk, &sA[rowbase * 64]);
            gl_lds16(gB + (size_t)rowbase * K + kk, &sB[rowbase * 64]);
        }
        __syncthreads();

#pragma unroll
        for (int kf = 0; kf < 2; ++kf) {
            int ch = ((kf * 4 + quad) ^ l7) << 3;     // swizzled chunk offset
            short8 af[4], bfr[4];
#pragma unroll
            for (int mt = 0; mt < 4; ++mt) {
                int m = wr * 64 + mt * 16 + l;        // m%8 == l%8
                af[mt] = *(const short8*)&sA[m * 64 + ch];
            }
#pragma unroll
            for (int nt = 0; nt < 4; ++nt) {
                int n = wc * 64 + nt * 16 + l;
                bfr[nt] = *(const short8*)&sB[n * 64 + ch];
            }
#pragma unroll
            for (int mt = 0; mt < 4; ++mt)
#pragma unroll
                for (int nt = 0; nt < 4; ++nt)
                    acc[mt][nt] = mfma16(af[mt], bfr[nt], acc[mt][nt]);
        }
        __syncthreads();
    }

    // epilogue
#pragma unroll
    for (int nt = 0; nt < 4; ++nt) {
        int colg = bN * 128 + wc * 64 + nt * 16 + l;
        float bv = bias ? bias[colg] : 0.f;
#pragma unroll
        for (int mt = 0; mt < 4; ++mt) {
#pragma unroll
            for (int rr = 0; rr < 4; ++rr) {
                int rowg = bM * 128 + wr * 64 + mt * 16 + quad * 4 + rr;
                float v = acc[mt][nt][rr] + bv;
                if (relu) v = fmaxf(v, 0.f);
                size_t idx = (size_t)rowg * N + colg;
                if (outF) outF[idx] = v;
                if (outB) outB[idx] = f2b(v);
            }
        }
    }
}

// ---------- flash attention v6: 32x32x16 MFMA, swapped QK^T, in-register P ----------
// QK^T computed as mfma(A=K, B=Q) 32x32x16 -> lane holds P^T[key][q=lane&31]:
// the whole P-row for one q lives in one lane-column pair, so the PV A-operand
// is built fully in registers with v_cvt_pk_bf16_f32 + v_permlane32_swap_b32
// (T12) -- no P LDS buffer, no P LDS traffic. K/V staged via global_load_lds
// (double-buffered, one barrier/iter) with 16B-granular XOR swizzle
// (LDS(row,cb) = G(row, cb ^ (row&7))), conflict-free ds_read_b128 fragments.
// No-max softmax (Q pre-scaled by QSCALE -> P = 2^s). One block = (b,h) x 128
// q-rows, 4 waves x 32 q-rows. LDS 32 KB -> 4 blocks/CU resident (no tail).
// grid: (B*H, S/128) -> all q-tiles of one (b,h) on the same XCD (L2 locality).
#define PACK8(sv, rb, dst) {                                                   \
    u32 pa_ = cvtpk(sv[rb + 0], sv[rb + 1]), pb_ = cvtpk(sv[rb + 4], sv[rb + 5]); \
    u32 pc_ = cvtpk(sv[rb + 2], sv[rb + 3]), pd_ = cvtpk(sv[rb + 6], sv[rb + 7]); \
    uint2v t0_ = __builtin_amdgcn_permlane32_swap(pa_, pb_, 0, 0);             \
    uint2v t1_ = __builtin_amdgcn_permlane32_swap(pc_, pd_, 0, 0);             \
    union { uint4v u; short8 s8; } cv_;                                        \
    cv_.u = (uint4v){t0_[0], t1_[0], t0_[1], t1_[1]};                          \
    dst = cv_.s8; }

__global__ __launch_bounds__(256, 4) void attn_kernel(const u16* __restrict__ qkv,
                                                      const u16* __restrict__ vt,
                                                      u16* __restrict__ ctx) {
    __shared__ __align__(16) u16 Kb[2][64 * 64];   // 16 KB
    __shared__ __align__(16) u16 Vb[2][64 * 64];   // 16 KB

    int bh = blockIdx.x; int b = bh >> 4, h = bh & 15;
    int tid = threadIdx.x;
    int w = tid >> 6, lane = tid & 63;
    int l32 = lane & 31, hi = lane >> 5, row7 = lane & 7;
    int qw = blockIdx.y * 128 + w * 32;  // this wave's first q-row

    // staging coords: lane covers (row = wbase + i*8 + r, colblk = c), fetching
    // global colblk (c ^ r) -> LDS XOR swizzle with row&7
    int r = lane >> 3, c = lane & 7;
    int cs = ((c ^ r) << 3);
    const u16* gK0 = qkv + (size_t)(b * S_ + w * 16 + r) * QKVS + 1024 + h * DH_ + cs;
    const u16* gK1 = gK0 + (size_t)8 * QKVS;
    const u16* gV0 = vt + (size_t)(bh * DH_ + w * 16 + r) * S_ + cs;
    const u16* gV1 = gV0 + (size_t)8 * S_;

    auto stage = [&](int bb) {
        u16* lk = &Kb[bb][w * 16 * 64];
        u16* lv = &Vb[bb][w * 16 * 64];
        gl_lds16(gK0, lk);
        gl_lds16(gK1, lk + 8 * 64);
        gl_lds16(gV0, lv);
        gl_lds16(gV1, lv + 8 * 64);
        gK0 += (size_t)64 * QKVS; gK1 += (size_t)64 * QKVS;
        gV0 += 64; gV1 += 64;
    };

    // Q B-fragments: B[n = q = l32][k = kc*16 + hi*8 + j], kept in registers
    short8 qf0, qf1, qf2, qf3;
    {
        const u16* qp = qkv + (size_t)(b * S_ + qw + l32) * QKVS + h * DH_ + hi * 8;
        qf0 = *(const short8*)(qp);
        qf1 = *(const short8*)(qp + 16);
        qf2 = *(const short8*)(qp + 32);
        qf3 = *(const short8*)(qp + 48);
    }

    floatx16 O0, O1;
#pragma unroll
    for (int i = 0; i < 16; ++i) { O0[i] = 0.f; O1[i] = 0.f; }
    float lra = 0.f, lrb = 0.f, lrc = 0.f, lrd = 0.f;  // denominator partials

    // per-lane LDS fragment row bases (elems); chunk = ((kc*2+hi) ^ row7) * 8
    int roff0 = l32 * 64;
    int roff1 = (32 + l32) * 64;

    stage(0);
    __syncthreads();

    const int NT = S_ / 64;
    for (int kt = 0; kt < NT; ++kt) {
        int cur = kt & 1;
        if (kt + 1 < NT) stage(cur ^ 1);

        const u16* Kc = Kb[cur];
        const u16* Vc = Vb[cur];

        // ---- S^T tile 0 (keys 0..31): A = K rows from LDS, B = Q regs ----
        floatx16 s0;
#pragma unroll
        for (int i = 0; i < 16; ++i) s0[i] = 0.f;
#pragma unroll
        for (int kc = 0; kc < 4; ++kc) {
            int ch = (((kc * 2 + hi) ^ row7) << 3);
            short8 ka = *(const short8*)&Kc[roff0 + ch];
            short8 qk = (kc == 0) ? qf0 : (kc == 1) ? qf1 : (kc == 2) ? qf2 : qf3;
            s0 = mfma32(ka, qk, s0);
        }
#pragma unroll
        for (int i = 0; i < 16; ++i) s0[i] = exp2f_hw(s0[i]);
        short8 pa0, pa1;
        PACK8(s0, 0, pa0);
        PACK8(s0, 8, pa1);

        // ---- S^T tile 1 (keys 32..63) ----
        floatx16 s1;
#pragma unroll
        for (int i = 0; i < 16; ++i) s1[i] = 0.f;
#pragma unroll
        for (int kc = 0; kc < 4; ++kc) {
            int ch = (((kc * 2 + hi) ^ row7) << 3);
            short8 ka = *(const short8*)&Kc[roff1 + ch];
            short8 qk = (kc == 0) ? qf0 : (kc == 1) ? qf1 : (kc == 2) ? qf2 : qf3;
            s1 = mfma32(ka, qk, s1);
        }
#pragma unroll
        for (int i = 0; i < 16; ++i) s1[i] = exp2f_hw(s1[i]);
        short8 pa2, pa3;
        PACK8(s1, 0, pa2);
        PACK8(s1, 8, pa3);

        // denominator partials (4 chains)
#pragma unroll
        for (int i = 0; i < 16; i += 4) {
            lra += s0[i + 0] + s1[i + 0];
            lrb += s0[i + 1] + s1[i + 1];
            lrc += s0[i + 2] + s1[i + 2];
            lrd += s0[i + 3] + s1[i + 3];
        }

        // ---- O += P @ V: A = pa regs, B = V^T rows (n = dh) from LDS ----
        {
            short8 vb0 = *(const short8*)&Vc[roff0 + (((0 + hi) ^ row7) << 3)];
            O0 = mfma32(pa0, vb0, O0);
            short8 vb1 = *(const short8*)&Vc[roff0 + (((2 + hi) ^ row7) << 3)];
            O0 = mfma32(pa1, vb1, O0);
            short8 vb2 = *(const short8*)&Vc[roff0 + (((4 + hi) ^ row7) << 3)];
            O0 = mfma32(pa2, vb2, O0);
            short8 vb3 = *(const short8*)&Vc[roff0 + (((6 + hi) ^ row7) << 3)];
            O0 = mfma32(pa3, vb3, O0);
        }
        {
            short8 vb0 = *(const short8*)&Vc[roff1 + (((0 + hi) ^ row7) << 3)];
            O1 = mfma32(pa0, vb0, O1);
            short8 vb1 = *(const short8*)&Vc[roff1 + (((2 + hi) ^ row7) << 3)];
            O1 = mfma32(pa1, vb1, O1);
            short8 vb2 = *(const short8*)&Vc[roff1 + (((4 + hi) ^ row7) << 3)];
            O1 = mfma32(pa2, vb2, O1);
            short8 vb3 = *(const short8*)&Vc[roff1 + (((6 + hi) ^ row7) << 3)];
            O1 = mfma32(pa3, vb3, O1);
        }

        __syncthreads();  // drains gl_lds (vmcnt) + protects buffer swap
    }

    // ---- epilogue: full denom = self + other half-wave; O /= lsum; store ----
    float lr = (lra + lrb) + (lrc + lrd);
    lr += __shfl_xor(lr, 32);
    float inv = 1.0f / lr;   // valid for q = l32 (both halves hold same sum)
#pragma unroll
    for (int rr = 0; rr < 16; ++rr) {
        int rowq = (rr & 3) + 8 * (rr >> 2) + 4 * hi;  // C/D row -> q within wave
        float iv = __shfl(inv, rowq);
        size_t base = (size_t)(b * S_ + qw + rowq) * D_ + h * DH_ + l32;
        ctx[base]      = f2b(O0[rr] * iv);
        ctx[base + 32] = f2b(O1[rr] * iv);
    }
}

// ---------- fused add + layernorm (one row of 1024 per block) ----------
__global__ __launch_bounds__(256) void add_ln(const float* __restrict__ a,
                                              const float* __restrict__ b,
                                              const float* __restrict__ g,
                                              const float* __restrict__ be,
                                              float* __restrict__ outF,
                                              u16* __restrict__ outB) {
    int row = blockIdx.x, tid = threadIdx.x;
    size_t base = (size_t)row * D_;
    float4 va = ((const float4*)(a + base))[tid];
    float4 vb = ((const float4*)(b + base))[tid];
    float x0 = va.x + vb.x, x1 = va.y + vb.y, x2 = va.z + vb.z, x3 = va.w + vb.w;
    float s1 = x0 + x1 + x2 + x3;
    float s2 = x0 * x0 + x1 * x1 + x2 * x2 + x3 * x3;
#pragma unroll
    for (int off = 32; off; off >>= 1) {
        s1 += __shfl_xor(s1, off);
        s2 += __shfl_xor(s2, off);
    }
    __shared__ float r1[4], r2[4];
    int w = tid >> 6, lane = tid & 63;
    if (lane == 0) { r1[w] = s1; r2[w] = s2; }
    __syncthreads();
    s1 = r1[0] + r1[1] + r1[2] + r1[3];
    s2 = r2[0] + r2[1] + r2[2] + r2[3];
    float mean = s1 * (1.0f / D_);
    float var = s2 * (1.0f / D_) - mean * mean;
    float inv = rsqrtf(var + 1e-6f);
    float4 vg = ((const float4*)g)[tid];
    float4 vbe = ((const float4*)be)[tid];
    float o0 = (x0 - mean) * inv * vg.x + vbe.x;
    float o1 = (x1 - mean) * inv * vg.y + vbe.y;
    float o2 = (x2 - mean) * inv * vg.z + vbe.z;
    float o3 = (x3 - mean) * inv * vg.w + vbe.w;
    float4 o; o.x = o0; o.y = o1; o.z = o2; o.w = o3;
    ((float4*)(outF + base))[tid] = o;
    if (outB) {
        ushort4 u;
        u.x = f2b(o0); u.y = f2b(o1); u.z = f2b(o2); u.w = f2b(o3);
        ((ushort4*)(outB + base))[tid] = u;
    }
}

extern "C" void kernel_launch(void* const* d_in, const int* in_sizes, int n_in,
                              void* d_out, int out_size, void* d_ws, size_t ws_size,
                              hipStream_t stream) {
    const float* x   = (const float*)d_in[0];
    const float* wq  = (const float*)d_in[1];
    const float* bq  = (const float*)d_in[2];
    const float* wk  = (const float*)d_in[3];
    const float* bk  = (const float*)d_in[4];
    const float* wv  = (const float*)d_in[5];
    const float* bv  = (const float*)d_in[6];
    const float* wo  = (const float*)d_in[7];
    const float* bo  = (const float*)d_in[8];
    const float* w1  = (const float*)d_in[9];
    const float* b1  = (const float*)d_in[10];
    const float* w2  = (const float*)d_in[11];
    const float* b2  = (const float*)d_in[12];
    const float* g1  = (const float*)d_in[13];
    const float* be1 = (const float*)d_in[14];
    const float* g2  = (const float*)d_in[15];
    const float* be2 = (const float*)d_in[16];
    float* out = (float*)d_out;
    char* ws = (char*)d_ws;
    const size_t MB = 1u << 20;

    // layout (185 MB total, with aliasing):
    u16* xb      = (u16*)(ws + 0);        // 16 MB (dead after QKV gemm)
    u16* wqkvT   = (u16*)(ws + 16 * MB);  // 6 MB [wq^T*QSCALE | wk^T | wv^T]
    u16* woT     = (u16*)(ws + 22 * MB);  // 2 MB
    u16* w1T     = (u16*)(ws + 24 * MB);  // 8 MB
    u16* w2T     = (u16*)(ws + 32 * MB);  // 8 MB
    float* qkvb  = (float*)(ws + 40 * MB);// 12 KB
    u16* qkv     = (u16*)(ws + 41 * MB);  // 48 MB (dead after attn)
    u16* vtb     = (u16*)(ws + 89 * MB);  // 16 MB (dead after attn)
    u16* ctxb    = (u16*)(ws + 105 * MB); // 16 MB
    float* attn_out = (float*)(ws + 121 * MB); // 32 MB (dead after add_ln1)
    float* out1     = (float*)(ws + 153 * MB); // 32 MB
    u16* out1b   = (u16*)(ws + 0);        // 16 MB, aliases dead xb
    u16* hidden  = (u16*)(ws + 41 * MB);  // 64 MB, aliases dead qkv+vtb
    float* ffn2out = (float*)(ws + 121 * MB); // aliases dead attn_out

    dim3 tb(32, 8);

    // prep: casts + weight transposes (wq pre-scaled by QSCALE = log2(e)/8)
    cast_b<<<8192, 256, 0, stream>>>(x, xb, (B_ * S_ * D_) / 4);
    transpose_cast<<<dim3(32, 32), tb, 0, stream>>>(wq, wqkvT, D_, D_, QSCALE);
    transpose_cast<<<dim3(32, 32), tb, 0, stream>>>(wk, wqkvT + 1024 * 1024, D_, D_, 1.0f);
    transpose_cast<<<dim3(32, 32), tb, 0, stream>>>(wv, wqkvT + 2048 * 1024, D_, D_, 1.0f);
    transpose_cast<<<dim3(32, 32), tb, 0, stream>>>(wo, woT, D_, D_, 1.0f);
    transpose_cast<<<dim3(128, 32), tb, 0, stream>>>(w1, w1T, D_, F_, 1.0f);
    transpose_cast<<<dim3(32, 128), tb, 0, stream>>>(w2, w2T, F_, D_, 1.0f);
    concat_bias<<<12, 256, 0, stream>>>(bq, bk, bv, qkvb);

    // fused QKV projection: [8192,1024] @ [3072,1024]^T -> qkv [8192,3072]
    gemm_bt<<<dim3(24, 64), 256, 0, stream>>>(xb, wqkvT, qkvb, nullptr, qkv,
                                              B_ * S_, QKVS, D_, 0);
    transpose_v<<<dim3(S_ / 32, DH_ / 32, B_ * H_), tb, 0, stream>>>(qkv, vtb);

    // attention (flash-style, 32x32 MFMA, in-register P, XCD-clustered per (b,h))
    attn_kernel<<<dim3(B_ * H_, S_ / 128), 256, 0, stream>>>(qkv, vtb, ctxb);

    // output projection (fp32 out, residual+LN done separately)
    gemm_bt<<<dim3(8, 64), 256, 0, stream>>>(ctxb, woT, bo, attn_out, nullptr,
                                             B_ * S_, D_, D_, 0);
    add_ln<<<B_ * S_, 256, 0, stream>>>(x, attn_out, g1, be1, out1, out1b);

    // FFN
    gemm_bt<<<dim3(32, 64), 256, 0, stream>>>(out1b, w1T, b1, nullptr, hidden,
                                              B_ * S_, F_, D_, 1);
    gemm_bt<<<dim3(8, 64), 256, 0, stream>>>(hidden, w2T, b2, ffn2out, nullptr,
                                             B_ * S_, D_, F_, 0);
    add_ln<<<B_ * S_, 256, 0, stream>>>(out1, ffn2out, g2, be2, out, nullptr);
}

// Round 2
// 551.274 us; speedup vs baseline: 1.0698x; 1.0018x over previous
//
#include <hip/hip_runtime.h>

typedef unsigned short u16;
typedef unsigned int u32;

typedef __attribute__((ext_vector_type(8))) short short8;
typedef __attribute__((ext_vector_type(4))) float floatx4;
typedef __attribute__((ext_vector_type(16))) float floatx16;
typedef __attribute__((ext_vector_type(2))) unsigned int uint2v;
typedef __attribute__((ext_vector_type(4))) unsigned int uint4v;

// ---------- bf16 helpers ----------
static __device__ __forceinline__ u16 f2b(float f) {
    union { float f; u32 i; } v; v.f = f;
    u32 r = v.i + 0x7fffu + ((v.i >> 16) & 1u);
    return (u16)(r >> 16);
}
// 2^x via v_exp_f32
static __device__ __forceinline__ float exp2f_hw(float x) {
    return __builtin_amdgcn_exp2f(x);
}
// pack two f32 -> bf16x2 dword (RNE) in one instruction
static __device__ __forceinline__ u32 cvtpk(float lo, float hi) {
    u32 r;
    asm("v_cvt_pk_bf16_f32 %0, %1, %2" : "=v"(r) : "v"(lo), "v"(hi));
    return r;
}

static __device__ __forceinline__ floatx4 mfma16(short8 a, short8 b, floatx4 c) {
    return __builtin_amdgcn_mfma_f32_16x16x32_bf16(a, b, c, 0, 0, 0);
}
static __device__ __forceinline__ floatx16 mfma32(short8 a, short8 b, floatx16 c) {
    return __builtin_amdgcn_mfma_f32_32x32x16_bf16(a, b, c, 0, 0, 0);
}

// async global->LDS, 16B per lane; LDS dest must be wave-uniform base (HW adds lane*16)
typedef __attribute__((address_space(1))) const void gas_void;
typedef __attribute__((address_space(3))) void las_void;
static __device__ __forceinline__ void gl_lds16(const void* g, void* l) {
    __builtin_amdgcn_global_load_lds((gas_void*)g, (las_void*)l, 16, 0, 0);
}

// counted vmcnt wait (T4) + raw barrier with compiler memory fence
template<int N> static __device__ __forceinline__ void vmw() {
    if constexpr (N == 0)  asm volatile("s_waitcnt vmcnt(0)" ::: "memory");
    else if constexpr (N == 4)  asm volatile("s_waitcnt vmcnt(4)" ::: "memory");
    else if constexpr (N == 8)  asm volatile("s_waitcnt vmcnt(8)" ::: "memory");
    else if constexpr (N == 9)  asm volatile("s_waitcnt vmcnt(9)" ::: "memory");
    else if constexpr (N == 12) asm volatile("s_waitcnt vmcnt(12)" ::: "memory");
}
#define SBAR() asm volatile("s_barrier" ::: "memory")

#define B_ 4
#define S_ 2048
#define D_ 1024
#define H_ 16
#define DH_ 64
#define F_ 4096
#define QKVS 3072   // row stride of fused qkv output

// (1/8) * log2(e), folded into wq/bq so logits come out in exp2 domain
#define QSCALE 0.18033688011112042f

// ---------- cast fp32 -> bf16, 4 elems/thread ----------
__global__ __launch_bounds__(256) void cast_b(const float* __restrict__ in,
                                              u16* __restrict__ out, int n4) {
    int id = blockIdx.x * 256 + threadIdx.x;
    if (id < n4) {
        float4 v = ((const float4*)in)[id];
        ushort4 u;
        u.x = f2b(v.x); u.y = f2b(v.y); u.z = f2b(v.z); u.w = f2b(v.w);
        ((ushort4*)out)[id] = u;
    }
}

// ---------- concat + scale bias: [bq*QSCALE | bk | bv] -> 3072 floats ----------
__global__ __launch_bounds__(256) void concat_bias(const float* __restrict__ bq,
                                                   const float* __restrict__ bk,
                                                   const float* __restrict__ bv,
                                                   float* __restrict__ o) {
    int i = blockIdx.x * 256 + threadIdx.x;
    float v;
    if (i < 1024) v = bq[i] * QSCALE;
    else if (i < 2048) v = bk[i - 1024];
    else v = bv[i - 2048];
    o[i] = v;
}

// ---------- transpose + cast + scale: in [R x C] fp32 -> out [C x R] bf16 ----------
__global__ void transpose_cast(const float* __restrict__ in, u16* __restrict__ out,
                               int R, int C, float scale) {
    __shared__ float t[32][33];
    int bx = blockIdx.x;  // over C
    int by = blockIdx.y;  // over R
    int x = threadIdx.x, y = threadIdx.y;  // 32x8
#pragma unroll
    for (int i = 0; i < 4; ++i) {
        int r = by * 32 + y + i * 8;
        t[y + i * 8][x] = in[(size_t)r * C + bx * 32 + x];
    }
    __syncthreads();
#pragma unroll
    for (int i = 0; i < 4; ++i) {
        int c = bx * 32 + y + i * 8;
        out[(size_t)c * R + by * 32 + x] = f2b(t[x][y + i * 8] * scale);
    }
}

// ---------- transpose V: qkv[B*S, 3072] cols 2048.. -> vt [B,H,DH,S] bf16 ----------
__global__ void transpose_v(const u16* __restrict__ qkv, u16* __restrict__ vt) {
    __shared__ u16 t[32][33];
    int bh = blockIdx.z; int b = bh >> 4, h = bh & 15;
    int s0 = blockIdx.x * 32, d0 = blockIdx.y * 32;
    int x = threadIdx.x, y = threadIdx.y;  // 32x8
#pragma unroll
    for (int i = 0; i < 4; ++i)
        t[y + i * 8][x] =
            qkv[(size_t)(b * S_ + s0 + y + i * 8) * QKVS + 2048 + h * DH_ + d0 + x];
    __syncthreads();
#pragma unroll
    for (int i = 0; i < 4; ++i)
        vt[((size_t)bh * DH_ + d0 + y + i * 8) * S_ + s0 + x] = t[x][y + i * 8];
}

// ---------- generic bf16 GEMM v2: C[M,N] = A[M,K] @ Bt[N,K]^T (+bias)(+relu) ----------
// 128x128 tile, 256 threads (4 waves in 2x2 of 64x64), BK=64 (32 MFMA/barrier),
// global_load_lds width=16 staging with 8-chunk XOR swizzle. Used for N=1024 GEMMs
// (gemm256's grid would only half-fill the device there).
__global__ __launch_bounds__(256) void gemm_bt(const u16* __restrict__ A,
                                               const u16* __restrict__ Bt,
                                               const float* __restrict__ bias,
                                               float* __restrict__ outF,
                                               u16* __restrict__ outB,
                                               int M, int N, int K, int relu) {
    __shared__ __align__(16) u16 sA[128 * 64];   // 16 KB
    __shared__ __align__(16) u16 sB[128 * 64];   // 16 KB

    int tid = threadIdx.x;
    int w = tid >> 6, lane = tid & 63, quad = lane >> 4, l = lane & 15;
    int wr = w >> 1, wc = w & 1;
    int bM = blockIdx.y, bN = blockIdx.x;

    floatx4 acc[4][4];
#pragma unroll
    for (int i = 0; i < 4; ++i)
#pragma unroll
        for (int j = 0; j < 4; ++j) acc[i][j] = (floatx4){0.f, 0.f, 0.f, 0.f};

    int r = lane >> 3;            // 0..7
    int c = lane & 7;             // 0..7
    int cg = ((c ^ r) << 3);      // global chunk offset in elems
    const u16* gA = &A[(size_t)(bM * 128 + r) * K + cg];
    const u16* gB = &Bt[(size_t)(bN * 128 + r) * K + cg];

    int l7 = l & 7;

    for (int kk = 0; kk < K; kk += 64) {
#pragma unroll
        for (int hh = 0; hh < 4; ++hh) {
            int rowbase = hh * 32 + w * 8;            // multiple of 8
            gl_lds16(gA + (size_t)rowbase * K + kk, &sA[rowbase * 64]);
            gl_lds16(gB + (size_t)rowbase * K + kk, &sB[rowbase * 64]);
        }
        __syncthreads();

#pragma unroll
        for (int kf = 0; kf < 2; ++kf) {
            int ch = ((kf * 4 + quad) ^ l7) << 3;     // swizzled chunk offset
            short8 af[4], bfr[4];
#pragma unroll
            for (int mt = 0; mt < 4; ++mt) {
                int m = wr * 64 + mt * 16 + l;        // m%8 == l%8
                af[mt] = *(const short8*)&sA[m * 64 + ch];
            }
#pragma unroll
            for (int nt = 0; nt < 4; ++nt) {
                int n = wc * 64 + nt * 16 + l;
                bfr[nt] = *(const short8*)&sB[n * 64 + ch];
            }
#pragma unroll
            for (int mt = 0; mt < 4; ++mt)
#pragma unroll
                for (int nt = 0; nt < 4; ++nt)
                    acc[mt][nt] = mfma16(af[mt], bfr[nt], acc[mt][nt]);
        }
        __syncthreads();
    }

#pragma unroll
    for (int nt = 0; nt < 4; ++nt) {
        int colg = bN * 128 + wc * 64 + nt * 16 + l;
        float bv = bias ? bias[colg] : 0.f;
#pragma unroll
        for (int mt = 0; mt < 4; ++mt) {
#pragma unroll
            for (int rr = 0; rr < 4; ++rr) {
                int rowg = bM * 128 + wr * 64 + mt * 16 + quad * 4 + rr;
                float v = acc[mt][nt][rr] + bv;
                if (relu) v = fmaxf(v, 0.f);
                size_t idx = (size_t)rowg * N + colg;
                if (outF) outF[idx] = v;
                if (outB) outB[idx] = f2b(v);
            }
        }
    }
}

// ---------- gemm256: 256x256 tile, 8-phase counted-vmcnt schedule (T2+T3+T4+T5) ----
// 512 threads = 8 waves (2M x 4N), each wave owns a 128x64 output; BK=64, 16x16x32
// MFMA. K-tile split into 4 chunks A(kh,mh) (128 rows x 32 cols = 8KB = 1 DMA issue)
// + 2 chunks B(kh) (256 rows x 32 cols = 16KB = 2 issues). Phase (mh,kh) consumes
// A(kh,mh)+B(kh): 8 ds_read_b128 + 16 MFMA; staging for tile t+2 is spread 1 chunk/
// phase into slots freed the previous phase. vmcnt is COUNTED (12/9 alternating,
// drain 12,8,8,4,4,0,0 in the last iteration) so 9-16 loads stay in flight across
// raw s_barriers -- never vmcnt(0) in the main loop. LDS slot s of row ri holds
// global 8-col group s^((ri>>1)&3): linear DMA dest + pre-swizzled source + same
// XOR on ds_read => conflict-free b128 frags (2-way max).
#define MFMA16X(MH)                                                        \
    __builtin_amdgcn_s_setprio(1);                                         \
    acc[(MH)*4+0][0] = mfma16(af0, bf0, acc[(MH)*4+0][0]);                 \
    acc[(MH)*4+0][1] = mfma16(af0, bf1, acc[(MH)*4+0][1]);                 \
    acc[(MH)*4+0][2] = mfma16(af0, bf2, acc[(MH)*4+0][2]);                 \
    acc[(MH)*4+0][3] = mfma16(af0, bf3, acc[(MH)*4+0][3]);                 \
    acc[(MH)*4+1][0] = mfma16(af1, bf0, acc[(MH)*4+1][0]);                 \
    acc[(MH)*4+1][1] = mfma16(af1, bf1, acc[(MH)*4+1][1]);                 \
    acc[(MH)*4+1][2] = mfma16(af1, bf2, acc[(MH)*4+1][2]);                 \
    acc[(MH)*4+1][3] = mfma16(af1, bf3, acc[(MH)*4+1][3]);                 \
    acc[(MH)*4+2][0] = mfma16(af2, bf0, acc[(MH)*4+2][0]);                 \
    acc[(MH)*4+2][1] = mfma16(af2, bf1, acc[(MH)*4+2][1]);                 \
    acc[(MH)*4+2][2] = mfma16(af2, bf2, acc[(MH)*4+2][2]);                 \
    acc[(MH)*4+2][3] = mfma16(af2, bf3, acc[(MH)*4+2][3]);                 \
    acc[(MH)*4+3][0] = mfma16(af3, bf0, acc[(MH)*4+3][0]);                 \
    acc[(MH)*4+3][1] = mfma16(af3, bf1, acc[(MH)*4+3][1]);                 \
    acc[(MH)*4+3][2] = mfma16(af3, bf2, acc[(MH)*4+3][2]);                 \
    acc[(MH)*4+3][3] = mfma16(af3, bf3, acc[(MH)*4+3][3]);                 \
    __builtin_amdgcn_s_setprio(0);

// one kh-pair: phase (mh=0,kh) then (mh=1,kh); B frags read once, reused across both
#define PPAIR(P, KH, ST0, VM0, ST1, VM1) {                                 \
    const u16* bBp = &smem[32768 + ((P)*2 + (KH)) * 8192];                 \
    short8 bf0 = *(const short8*)&bBp[boff];                               \
    short8 bf1 = *(const short8*)&bBp[boff + 512];                         \
    short8 bf2 = *(const short8*)&bBp[boff + 1024];                        \
    short8 bf3 = *(const short8*)&bBp[boff + 1536];                        \
    {   const u16* bAp = &smem[((P)*4 + (KH)*2 + 0) * 4096];               \
        short8 af0 = *(const short8*)&bAp[aoff];                           \
        short8 af1 = *(const short8*)&bAp[aoff + 512];                     \
        short8 af2 = *(const short8*)&bAp[aoff + 1024];                    \
        short8 af3 = *(const short8*)&bAp[aoff + 1536];                    \
        ST0;                                                               \
        MFMA16X(0)                                                         \
        vmw<VM0>(); SBAR();                                                \
    }                                                                      \
    {   const u16* bAp = &smem[((P)*4 + (KH)*2 + 1) * 4096];               \
        short8 af0 = *(const short8*)&bAp[aoff];                           \
        short8 af1 = *(const short8*)&bAp[aoff + 512];                     \
        short8 af2 = *(const short8*)&bAp[aoff + 1024];                    \
        short8 af3 = *(const short8*)&bAp[aoff + 1536];                    \
        ST1;                                                               \
        MFMA16X(1)                                                         \
        vmw<VM1>(); SBAR();                                                \
    } }

__global__ __launch_bounds__(512) void gemm256(const u16* __restrict__ A,
                                               const u16* __restrict__ Bt,
                                               const float* __restrict__ bias,
                                               float* __restrict__ outF,
                                               u16* __restrict__ outB,
                                               int M, int N, int K, int relu) {
    __shared__ __align__(16) u16 smem[65536];   // 128 KB: A 64 KB + B 64 KB

    int tid = threadIdx.x;
    int w = tid >> 6, lane = tid & 63, quad = lane >> 4, l = lane & 15;
    int wr = w >> 2, wc = w & 3;

    // XCD-aware bijective block swizzle (grid % 8 == 0 for all our shapes)
    int nbN = gridDim.x, nwg = gridDim.x * gridDim.y;
    int flat = blockIdx.y * gridDim.x + blockIdx.x;
    int swz = (flat & 7) * (nwg >> 3) + (flat >> 3);
    int bM = swz / nbN, bN = swz % nbN;

    floatx4 acc[8][4];
#pragma unroll
    for (int i = 0; i < 8; ++i)
#pragma unroll
        for (int j = 0; j < 4; ++j) acc[i][j] = (floatx4){0.f, 0.f, 0.f, 0.f};

    // staging: per 8KB issue, lane covers LDS o16 = w*64+lane -> (ri = o16>>2,
    // slot s = lane&3); source col-group g = s ^ ((ri>>1)&3) = (lane&3)^((lane>>3)&3)
    int g8 = (((lane & 3) ^ ((lane >> 3) & 3)) << 3);
    int rA = ((w >> 2) << 7) + ((w & 3) << 4) + (lane >> 2);  // A ri -> row map
    int rB = (w << 4) + (lane >> 2);                          // B ri within half
    const u16* gAb = A + (size_t)(bM * 256 + rA) * K + g8;
    const u16* gBb = Bt + (size_t)(bN * 256 + rB) * K + g8;

    auto stA = [&](int p, int kh, int mh, int t) {
        gl_lds16(gAb + (size_t)(mh * 64) * K + t * 64 + kh * 32,
                 (void*)&smem[((p << 2) + (kh << 1) + mh) * 4096 + (w << 9)]);
    };
    auto stB = [&](int p, int kh, int hb, int t) {
        gl_lds16(gBb + (size_t)(hb * 128) * K + t * 64 + kh * 32,
                 (void*)&smem[32768 + ((p << 1) + kh) * 8192 + hb * 4096 + (w << 9)]);
    };

    // fragment-read bases: slot s = quad ^ ((l>>1)&3), row ri = (wr|wc)*64 + i*16 + l
    int sQ = ((quad ^ ((l >> 1) & 3)) << 3);
    int aoff = ((wr << 6) + l) * 32 + sQ;
    int boff = ((wc << 6) + l) * 32 + sQ;

    // prologue: tile0 full (in steady-state order), tile1 first five
    stA(0, 0, 0, 0); stA(0, 0, 1, 0); stB(0, 0, 0, 0); stB(0, 0, 1, 0);
    stA(0, 1, 0, 0); stA(0, 1, 1, 0); stB(0, 1, 0, 0); stB(0, 1, 1, 0);
    stA(1, 0, 0, 1); stA(1, 0, 1, 1); stB(1, 0, 0, 1); stB(1, 0, 1, 1);
    stA(1, 1, 0, 1);
    vmw<9>(); SBAR();

    const int KT = K >> 6;
    for (int i = 0; i < (KT >> 1) - 1; ++i) {
        int t1 = 2 * i + 1, t2 = 2 * i + 2, t3 = 2 * i + 3;
        PPAIR(0, 0, (stA(1,1,1,t1), stB(1,1,0,t1), stB(1,1,1,t1)), 12, (stA(0,0,0,t2)), 9)
        PPAIR(0, 1, (stA(0,0,1,t2), stB(0,0,0,t2), stB(0,0,1,t2)), 12, (stA(0,1,0,t2)), 9)
        PPAIR(1, 0, (stA(0,1,1,t2), stB(0,1,0,t2), stB(0,1,1,t2)), 12, (stA(1,0,0,t3)), 9)
        PPAIR(1, 1, (stA(1,0,1,t3), stB(1,0,0,t3), stB(1,0,1,t3)), 12, (stA(1,1,0,t3)), 9)
    }
    {   // last iteration: only tile KT-1's leftovers staged at P1, then drain
        int t1 = KT - 1;
        PPAIR(0, 0, (stA(1,1,1,t1), stB(1,1,0,t1), stB(1,1,1,t1)), 12, ((void)0), 8)
        PPAIR(0, 1, ((void)0), 8, ((void)0), 4)
        PPAIR(1, 0, ((void)0), 4, ((void)0), 0)
        PPAIR(1, 1, ((void)0), 0, ((void)0), 0)
    }

    // epilogue
#pragma unroll
    for (int nt = 0; nt < 4; ++nt) {
        int colg = bN * 256 + wc * 64 + nt * 16 + l;
        float bv = bias ? bias[colg] : 0.f;
#pragma unroll
        for (int mt = 0; mt < 8; ++mt) {
#pragma unroll
            for (int rr = 0; rr < 4; ++rr) {
                int rowg = bM * 256 + wr * 128 + mt * 16 + quad * 4 + rr;
                float v = acc[mt][nt][rr] + bv;
                if (relu) v = fmaxf(v, 0.f);
                size_t idx = (size_t)rowg * N + colg;
                if (outF) outF[idx] = v;
                if (outB) outB[idx] = f2b(v);
            }
        }
    }
}

// ---------- flash attention v6: 32x32x16 MFMA, swapped QK^T, in-register P ----------
#define PACK8(sv, rb, dst) {                                                   \
    u32 pa_ = cvtpk(sv[rb + 0], sv[rb + 1]), pb_ = cvtpk(sv[rb + 4], sv[rb + 5]); \
    u32 pc_ = cvtpk(sv[rb + 2], sv[rb + 3]), pd_ = cvtpk(sv[rb + 6], sv[rb + 7]); \
    uint2v t0_ = __builtin_amdgcn_permlane32_swap(pa_, pb_, 0, 0);             \
    uint2v t1_ = __builtin_amdgcn_permlane32_swap(pc_, pd_, 0, 0);             \
    union { uint4v u; short8 s8; } cv_;                                        \
    cv_.u = (uint4v){t0_[0], t1_[0], t0_[1], t1_[1]};                          \
    dst = cv_.s8; }

__global__ __launch_bounds__(256, 4) void attn_kernel(const u16* __restrict__ qkv,
                                                      const u16* __restrict__ vt,
                                                      u16* __restrict__ ctx) {
    __shared__ __align__(16) u16 Kb[2][64 * 64];   // 16 KB
    __shared__ __align__(16) u16 Vb[2][64 * 64];   // 16 KB

    int bh = blockIdx.x; int b = bh >> 4, h = bh & 15;
    int tid = threadIdx.x;
    int w = tid >> 6, lane = tid & 63;
    int l32 = lane & 31, hi = lane >> 5, row7 = lane & 7;
    int qw = blockIdx.y * 128 + w * 32;  // this wave's first q-row

    int r = lane >> 3, c = lane & 7;
    int cs = ((c ^ r) << 3);
    const u16* gK0 = qkv + (size_t)(b * S_ + w * 16 + r) * QKVS + 1024 + h * DH_ + cs;
    const u16* gK1 = gK0 + (size_t)8 * QKVS;
    const u16* gV0 = vt + (size_t)(bh * DH_ + w * 16 + r) * S_ + cs;
    const u16* gV1 = gV0 + (size_t)8 * S_;

    auto stage = [&](int bb) {
        u16* lk = &Kb[bb][w * 16 * 64];
        u16* lv = &Vb[bb][w * 16 * 64];
        gl_lds16(gK0, lk);
        gl_lds16(gK1, lk + 8 * 64);
        gl_lds16(gV0, lv);
        gl_lds16(gV1, lv + 8 * 64);
        gK0 += (size_t)64 * QKVS; gK1 += (size_t)64 * QKVS;
        gV0 += 64; gV1 += 64;
    };

    // Q B-fragments: B[n = q = l32][k = kc*16 + hi*8 + j], kept in registers
    short8 qf0, qf1, qf2, qf3;
    {
        const u16* qp = qkv + (size_t)(b * S_ + qw + l32) * QKVS + h * DH_ + hi * 8;
        qf0 = *(const short8*)(qp);
        qf1 = *(const short8*)(qp + 16);
        qf2 = *(const short8*)(qp + 32);
        qf3 = *(const short8*)(qp + 48);
    }

    floatx16 O0, O1;
#pragma unroll
    for (int i = 0; i < 16; ++i) { O0[i] = 0.f; O1[i] = 0.f; }
    float lra = 0.f, lrb = 0.f, lrc = 0.f, lrd = 0.f;  // denominator partials

    int roff0 = l32 * 64;
    int roff1 = (32 + l32) * 64;

    stage(0);
    __syncthreads();

    const int NT = S_ / 64;
    for (int kt = 0; kt < NT; ++kt) {
        int cur = kt & 1;
        if (kt + 1 < NT) stage(cur ^ 1);

        const u16* Kc = Kb[cur];
        const u16* Vc = Vb[cur];

        // ---- S^T tile 0 (keys 0..31): A = K rows from LDS, B = Q regs ----
        floatx16 s0;
#pragma unroll
        for (int i = 0; i < 16; ++i) s0[i] = 0.f;
#pragma unroll
        for (int kc = 0; kc < 4; ++kc) {
            int ch = (((kc * 2 + hi) ^ row7) << 3);
            short8 ka = *(const short8*)&Kc[roff0 + ch];
            short8 qk = (kc == 0) ? qf0 : (kc == 1) ? qf1 : (kc == 2) ? qf2 : qf3;
            s0 = mfma32(ka, qk, s0);
        }
#pragma unroll
        for (int i = 0; i < 16; ++i) s0[i] = exp2f_hw(s0[i]);
        short8 pa0, pa1;
        PACK8(s0, 0, pa0);
        PACK8(s0, 8, pa1);

        // ---- S^T tile 1 (keys 32..63) ----
        floatx16 s1;
#pragma unroll
        for (int i = 0; i < 16; ++i) s1[i] = 0.f;
#pragma unroll
        for (int kc = 0; kc < 4; ++kc) {
            int ch = (((kc * 2 + hi) ^ row7) << 3);
            short8 ka = *(const short8*)&Kc[roff1 + ch];
            short8 qk = (kc == 0) ? qf0 : (kc == 1) ? qf1 : (kc == 2) ? qf2 : qf3;
            s1 = mfma32(ka, qk, s1);
        }
#pragma unroll
        for (int i = 0; i < 16; ++i) s1[i] = exp2f_hw(s1[i]);
        short8 pa2, pa3;
        PACK8(s1, 0, pa2);
        PACK8(s1, 8, pa3);

        // denominator partials (4 chains)
#pragma unroll
        for (int i = 0; i < 16; i += 4) {
            lra += s0[i + 0] + s1[i + 0];
            lrb += s0[i + 1] + s1[i + 1];
            lrc += s0[i + 2] + s1[i + 2];
            lrd += s0[i + 3] + s1[i + 3];
        }

        // ---- O += P @ V: A = pa regs, B = V^T rows (n = dh) from LDS ----
        {
            short8 vb0 = *(const short8*)&Vc[roff0 + (((0 + hi) ^ row7) << 3)];
            O0 = mfma32(pa0, vb0, O0);
            short8 vb1 = *(const short8*)&Vc[roff0 + (((2 + hi) ^ row7) << 3)];
            O0 = mfma32(pa1, vb1, O0);
            short8 vb2 = *(const short8*)&Vc[roff0 + (((4 + hi) ^ row7) << 3)];
            O0 = mfma32(pa2, vb2, O0);
            short8 vb3 = *(const short8*)&Vc[roff0 + (((6 + hi) ^ row7) << 3)];
            O0 = mfma32(pa3, vb3, O0);
        }
        {
            short8 vb0 = *(const short8*)&Vc[roff1 + (((0 + hi) ^ row7) << 3)];
            O1 = mfma32(pa0, vb0, O1);
            short8 vb1 = *(const short8*)&Vc[roff1 + (((2 + hi) ^ row7) << 3)];
            O1 = mfma32(pa1, vb1, O1);
            short8 vb2 = *(const short8*)&Vc[roff1 + (((4 + hi) ^ row7) << 3)];
            O1 = mfma32(pa2, vb2, O1);
            short8 vb3 = *(const short8*)&Vc[roff1 + (((6 + hi) ^ row7) << 3)];
            O1 = mfma32(pa3, vb3, O1);
        }

        __syncthreads();  // drains gl_lds (vmcnt) + protects buffer swap
    }

    // ---- epilogue: full denom = self + other half-wave; O /= lsum; store ----
    float lr = (lra + lrb) + (lrc + lrd);
    lr += __shfl_xor(lr, 32);
    float inv = 1.0f / lr;   // valid for q = l32 (both halves hold same sum)
#pragma unroll
    for (int rr = 0; rr < 16; ++rr) {
        int rowq = (rr & 3) + 8 * (rr >> 2) + 4 * hi;  // C/D row -> q within wave
        float iv = __shfl(inv, rowq);
        size_t base = (size_t)(b * S_ + qw + rowq) * D_ + h * DH_ + l32;
        ctx[base]      = f2b(O0[rr] * iv);
        ctx[base + 32] = f2b(O1[rr] * iv);
    }
}

// ---------- fused add + layernorm (one row of 1024 per block) ----------
__global__ __launch_bounds__(256) void add_ln(const float* __restrict__ a,
                                              const float* __restrict__ b,
                                              const float* __restrict__ g,
                                              const float* __restrict__ be,
                                              float* __restrict__ outF,
                                              u16* __restrict__ outB) {
    int row = blockIdx.x, tid = threadIdx.x;
    size_t base = (size_t)row * D_;
    float4 va = ((const float4*)(a + base))[tid];
    float4 vb = ((const float4*)(b + base))[tid];
    float x0 = va.x + vb.x, x1 = va.y + vb.y, x2 = va.z + vb.z, x3 = va.w + vb.w;
    float s1 = x0 + x1 + x2 + x3;
    float s2 = x0 * x0 + x1 * x1 + x2 * x2 + x3 * x3;
#pragma unroll
    for (int off = 32; off; off >>= 1) {
        s1 += __shfl_xor(s1, off);
        s2 += __shfl_xor(s2, off);
    }
    __shared__ float r1[4], r2[4];
    int w = tid >> 6, lane = tid & 63;
    if (lane == 0) { r1[w] = s1; r2[w] = s2; }
    __syncthreads();
    s1 = r1[0] + r1[1] + r1[2] + r1[3];
    s2 = r2[0] + r2[1] + r2[2] + r2[3];
    float mean = s1 * (1.0f / D_);
    float var = s2 * (1.0f / D_) - mean * mean;
    float inv = rsqrtf(var + 1e-6f);
    float4 vg = ((const float4*)g)[tid];
    float4 vbe = ((const float4*)be)[tid];
    float o0 = (x0 - mean) * inv * vg.x + vbe.x;
    float o1 = (x1 - mean) * inv * vg.y + vbe.y;
    float o2 = (x2 - mean) * inv * vg.z + vbe.z;
    float o3 = (x3 - mean) * inv * vg.w + vbe.w;
    float4 o; o.x = o0; o.y = o1; o.z = o2; o.w = o3;
    ((float4*)(outF + base))[tid] = o;
    if (outB) {
        ushort4 u;
        u.x = f2b(o0); u.y = f2b(o1); u.z = f2b(o2); u.w = f2b(o3);
        ((ushort4*)(outB + base))[tid] = u;
    }
}

extern "C" void kernel_launch(void* const* d_in, const int* in_sizes, int n_in,
                              void* d_out, int out_size, void* d_ws, size_t ws_size,
                              hipStream_t stream) {
    const float* x   = (const float*)d_in[0];
    const float* wq  = (const float*)d_in[1];
    const float* bq  = (const float*)d_in[2];
    const float* wk  = (const float*)d_in[3];
    const float* bk  = (const float*)d_in[4];
    const float* wv  = (const float*)d_in[5];
    const float* bv  = (const float*)d_in[6];
    const float* wo  = (const float*)d_in[7];
    const float* bo  = (const float*)d_in[8];
    const float* w1  = (const float*)d_in[9];
    const float* b1  = (const float*)d_in[10];
    const float* w2  = (const float*)d_in[11];
    const float* b2  = (const float*)d_in[12];
    const float* g1  = (const float*)d_in[13];
    const float* be1 = (const float*)d_in[14];
    const float* g2  = (const float*)d_in[15];
    const float* be2 = (const float*)d_in[16];
    float* out = (float*)d_out;
    char* ws = (char*)d_ws;
    const size_t MB = 1u << 20;

    // layout (185 MB total, with aliasing):
    u16* xb      = (u16*)(ws + 0);        // 16 MB (dead after QKV gemm)
    u16* wqkvT   = (u16*)(ws + 16 * MB);  // 6 MB [wq^T*QSCALE | wk^T | wv^T]
    u16* woT     = (u16*)(ws + 22 * MB);  // 2 MB
    u16* w1T     = (u16*)(ws + 24 * MB);  // 8 MB
    u16* w2T     = (u16*)(ws + 32 * MB);  // 8 MB
    float* qkvb  = (float*)(ws + 40 * MB);// 12 KB
    u16* qkv     = (u16*)(ws + 41 * MB);  // 48 MB (dead after attn)
    u16* vtb     = (u16*)(ws + 89 * MB);  // 16 MB (dead after attn)
    u16* ctxb    = (u16*)(ws + 105 * MB); // 16 MB
    float* attn_out = (float*)(ws + 121 * MB); // 32 MB (dead after add_ln1)
    float* out1     = (float*)(ws + 153 * MB); // 32 MB
    u16* out1b   = (u16*)(ws + 0);        // 16 MB, aliases dead xb
    u16* hidden  = (u16*)(ws + 41 * MB);  // 64 MB, aliases dead qkv+vtb
    float* ffn2out = (float*)(ws + 121 * MB); // aliases dead attn_out

    dim3 tb(32, 8);

    // prep: casts + weight transposes (wq pre-scaled by QSCALE = log2(e)/8)
    cast_b<<<8192, 256, 0, stream>>>(x, xb, (B_ * S_ * D_) / 4);
    transpose_cast<<<dim3(32, 32), tb, 0, stream>>>(wq, wqkvT, D_, D_, QSCALE);
    transpose_cast<<<dim3(32, 32), tb, 0, stream>>>(wk, wqkvT + 1024 * 1024, D_, D_, 1.0f);
    transpose_cast<<<dim3(32, 32), tb, 0, stream>>>(wv, wqkvT + 2048 * 1024, D_, D_, 1.0f);
    transpose_cast<<<dim3(32, 32), tb, 0, stream>>>(wo, woT, D_, D_, 1.0f);
    transpose_cast<<<dim3(128, 32), tb, 0, stream>>>(w1, w1T, D_, F_, 1.0f);
    transpose_cast<<<dim3(32, 128), tb, 0, stream>>>(w2, w2T, F_, D_, 1.0f);
    concat_bias<<<12, 256, 0, stream>>>(bq, bk, bv, qkvb);

    // fused QKV projection: [8192,1024] @ [3072,1024]^T -> qkv [8192,3072]
    gemm256<<<dim3(12, 32), 512, 0, stream>>>(xb, wqkvT, qkvb, nullptr, qkv,
                                              B_ * S_, QKVS, D_, 0);
    transpose_v<<<dim3(S_ / 32, DH_ / 32, B_ * H_), tb, 0, stream>>>(qkv, vtb);

    // attention (flash-style, 32x32 MFMA, in-register P, XCD-clustered per (b,h))
    attn_kernel<<<dim3(B_ * H_, S_ / 128), 256, 0, stream>>>(qkv, vtb, ctxb);

    // output projection (fp32 out, residual+LN done separately)
    gemm_bt<<<dim3(8, 64), 256, 0, stream>>>(ctxb, woT, bo, attn_out, nullptr,
                                             B_ * S_, D_, D_, 0);
    add_ln<<<B_ * S_, 256, 0, stream>>>(x, attn_out, g1, be1, out1, out1b);

    // FFN
    gemm256<<<dim3(16, 32), 512, 0, stream>>>(out1b, w1T, b1, nullptr, hidden,
                                              B_ * S_, F_, D_, 1);
    gemm_bt<<<dim3(8, 64), 256, 0, stream>>>(hidden, w2T, b2, ffn2out, nullptr,
                                             B_ * S_, D_, F_, 0);
    add_ln<<<B_ * S_, 256, 0, stream>>>(out1, ffn2out, g2, be2, out, nullptr);
}